// Round 6
// baseline (50.904 us; speedup 1.0000x reference)
//
#include <hip/hip_runtime.h>
#include <math.h>

#define DDIM 512
#define BDIM 256
#define NCLS 85742
#define NB1 2048
#define CHUNK1 ((NCLS + NB1 - 1) / NB1)   // 42 rows per block

__device__ __forceinline__ float wave_reduce(float v) {
    #pragma unroll
    for (int off = 32; off > 0; off >>= 1)
        v += __shfl_down(v, off, 64);
    return v;
}

__device__ __forceinline__ float block_reduce(float v, float* smem) {
    const int lane = threadIdx.x & 63;
    const int wid  = threadIdx.x >> 6;
    v = wave_reduce(v);
    if (lane == 0) smem[wid] = v;
    __syncthreads();
    if (wid == 0) {
        v = (lane < (int)(blockDim.x >> 6)) ? smem[lane] : 0.0f;
        v = wave_reduce(v);
    }
    return v;
}

// K1: per-block column partials over a contiguous 42-row chunk.
// thread t: quad q=t&127, row parity rsub=t>>7. 4-deep ILP (~48 VGPR).
// launch_bounds(256,8) caps VGPR at 64 -> 8 waves/SIMD; 2048 blocks = 8
// blocks/CU = 32 waves/CU (grid was the occupancy limiter before).
// Partials stored TRANSPOSED: partialT[q*NB1 + b]. Empty blocks write zeros.
__global__ __launch_bounds__(256, 8)
void colsum_partial(const float* __restrict__ W, float4* __restrict__ partialT) {
    const int t = threadIdx.x;
    const int q = t & 127;
    const int rsub = t >> 7;
    const int b = blockIdx.x;
    const float4* __restrict__ W4 = reinterpret_cast<const float4*>(W);

    const int r0 = b * CHUNK1;
    const int r1 = (r0 + CHUNK1 < NCLS) ? r0 + CHUNK1 : NCLS;

    float4 a0 = make_float4(0.f, 0.f, 0.f, 0.f);
    float4 a1 = a0, a2 = a0, a3 = a0;
    int r = r0 + rsub;                       // rows stride 2 (parity split)
    for (; r + 6 < r1; r += 8) {
        float4 v0 = W4[(size_t)(r    ) * 128 + q];
        float4 v1 = W4[(size_t)(r + 2) * 128 + q];
        float4 v2 = W4[(size_t)(r + 4) * 128 + q];
        float4 v3 = W4[(size_t)(r + 6) * 128 + q];
        a0.x += v0.x; a0.y += v0.y; a0.z += v0.z; a0.w += v0.w;
        a1.x += v1.x; a1.y += v1.y; a1.z += v1.z; a1.w += v1.w;
        a2.x += v2.x; a2.y += v2.y; a2.z += v2.z; a2.w += v2.w;
        a3.x += v3.x; a3.y += v3.y; a3.z += v3.z; a3.w += v3.w;
    }
    for (; r < r1; r += 2) {
        float4 v = W4[(size_t)r * 128 + q];
        a0.x += v.x; a0.y += v.y; a0.z += v.z; a0.w += v.w;
    }
    a0.x += a1.x + a2.x + a3.x;
    a0.y += a1.y + a2.y + a3.y;
    a0.z += a1.z + a2.z + a3.z;
    a0.w += a1.w + a2.w + a3.w;

    __shared__ float4 smem[128];
    if (rsub) smem[q] = a0;
    __syncthreads();
    if (!rsub) {
        float4 o = smem[q];
        a0.x += o.x; a0.y += o.y; a0.z += o.z; a0.w += o.w;
        partialT[(size_t)q * NB1 + b] = a0;
    }
}

// K2: colsum quad q = sum of partialT[q*NB1 .. +2047]. Block 0 also zeroes
// the scalar accumulators (sums, out) consumed downstream.
__global__ __launch_bounds__(256, 4)
void colsum_reduce(const float4* __restrict__ partialT, float* __restrict__ colsum,
                   float* __restrict__ sums, float* __restrict__ out) {
    const int q = blockIdx.x;       // 0..127
    const int t = threadIdx.x;
    if (q == 0 && t < 3) {
        if (t < 2) sums[t] = 0.0f;
        else *out = 0.0f;
    }
    const float4* __restrict__ p = partialT + (size_t)q * NB1;
    float sx = 0.f, sy = 0.f, sz = 0.f, sw = 0.f;
    #pragma unroll
    for (int k = 0; k < NB1 / 256; ++k) {
        float4 v = p[t + k * 256];
        sx += v.x; sy += v.y; sz += v.z; sw += v.w;
    }
    sx = wave_reduce(sx); sy = wave_reduce(sy);
    sz = wave_reduce(sz); sw = wave_reduce(sw);
    __shared__ float4 sm[4];
    if ((t & 63) == 0) sm[t >> 6] = make_float4(sx, sy, sz, sw);
    __syncthreads();
    if (t == 0) {
        float4 r0 = sm[0], r1 = sm[1], r2 = sm[2], r3 = sm[3];
        colsum[q * 4 + 0] = (r0.x + r1.x) + (r2.x + r3.x);
        colsum[q * 4 + 1] = (r0.y + r1.y) + (r2.y + r3.y);
        colsum[q * 4 + 2] = (r0.z + r1.z) + (r2.z + r3.z);
        colsum[q * 4 + 3] = (r0.w + r1.w) + (r2.w + r3.w);
    }
}

// K3: Sy = sum (wy-mu)^2 ; Si = sum (colsum - wy - mu)^2   over B*D elements
__global__ void dist_kernel(const float* __restrict__ mu,
                            const float* __restrict__ W,
                            const int*   __restrict__ label,
                            const float* __restrict__ colsum,
                            float* __restrict__ sums) {
    __shared__ float smem[8];
    float dy2 = 0.0f, di2 = 0.0f;
    const int n = BDIM * DDIM;
    for (int i = blockIdx.x * blockDim.x + threadIdx.x; i < n;
         i += gridDim.x * blockDim.x) {
        const int b = i >> 9;        // i / 512
        const int d = i & 511;       // i % 512
        const float w = W[(size_t)label[b] * DDIM + d];
        const float m = mu[i];
        const float a = w - m;
        dy2 += a * a;
        const float c = colsum[d] - w - m;
        di2 += c * c;
    }
    dy2 = block_reduce(dy2, smem);
    __syncthreads();
    di2 = block_reduce(di2, smem);
    if (threadIdx.x == 0) {
        atomicAdd(&sums[0], dy2);
        atomicAdd(&sums[1], di2);
    }
}

// K4: loss = sum erf(dy/(sqrt2*std)) + erfc(di/(sqrt2*std))
__global__ void loss_kernel(const float* __restrict__ stdv,
                            const float* __restrict__ sums,
                            float* __restrict__ out) {
    __shared__ float smem[8];
    const float dy = sqrtf(sums[0]);
    const float di = sqrtf(sums[1]);
    const float inv_sqrt2 = 0.70710678118654752f;
    float acc = 0.0f;
    const int n = BDIM * DDIM;
    for (int i = blockIdx.x * blockDim.x + threadIdx.x; i < n;
         i += gridDim.x * blockDim.x) {
        const float s = stdv[i];
        const float r = inv_sqrt2 / s;
        acc += erff(dy * r) + erfcf(di * r);
    }
    acc = block_reduce(acc, smem);
    if (threadIdx.x == 0) atomicAdd(out, acc);
}

extern "C" void kernel_launch(void* const* d_in, const int* in_sizes, int n_in,
                              void* d_out, int out_size, void* d_ws, size_t ws_size,
                              hipStream_t stream) {
    // inputs: 0=x (unused), 1=mu, 2=std, 3=weight, 4=label
    const float* mu    = (const float*)d_in[1];
    const float* stdv  = (const float*)d_in[2];
    const float* W     = (const float*)d_in[3];
    const int*   label = (const int*)d_in[4];
    float* out = (float*)d_out;
    float* ws  = (float*)d_ws;
    // ws layout: [0..511]=colsum, [512],[513]=Sy,Si, floats [1024 ...) = partialT (4 MB)
    float4* partialT = (float4*)(ws + 1024);

    colsum_partial<<<NB1, 256, 0, stream>>>(W, partialT);
    colsum_reduce<<<128, 256, 0, stream>>>(partialT, ws, ws + 512, out);
    dist_kernel<<<256, 256, 0, stream>>>(mu, W, label, ws, ws + 512);
    loss_kernel<<<256, 256, 0, stream>>>(stdv, ws + 512, out);
}

// Round 8
// 50.016 us; speedup vs baseline: 1.0178x; 1.0178x over previous
//
#include <hip/hip_runtime.h>
#include <math.h>

#define DDIM 512
#define BDIM 256
#define NCLS 85742
#define NB1 2048
#define CHUNK1 ((NCLS + NB1 - 1) / NB1)   // 42 rows per block

typedef float f32x4 __attribute__((ext_vector_type(4)));
#define NTL(p) __builtin_nontemporal_load(p)

__device__ __forceinline__ float wave_reduce(float v) {
    #pragma unroll
    for (int off = 32; off > 0; off >>= 1)
        v += __shfl_down(v, off, 64);
    return v;
}

__device__ __forceinline__ float block_reduce(float v, float* smem) {
    const int lane = threadIdx.x & 63;
    const int wid  = threadIdx.x >> 6;
    v = wave_reduce(v);
    if (lane == 0) smem[wid] = v;
    __syncthreads();
    if (wid == 0) {
        v = (lane < (int)(blockDim.x >> 6)) ? smem[lane] : 0.0f;
        v = wave_reduce(v);
    }
    return v;
}

// K1: per-block column partials over a contiguous 42-row chunk.
// Nontemporal loads (read-once stream: skip cache allocation) + explicit
// 4-stage rotating-register pipeline (force 4 loads in flight).
// Block 0 also zeroes the scalar accumulators (replaces memsets).
__global__ __launch_bounds__(256, 4)
void colsum_partial(const float* __restrict__ W, f32x4* __restrict__ partialT,
                    float* __restrict__ sums, float* __restrict__ out) {
    const int t = threadIdx.x;
    if (blockIdx.x == 0) {
        if (t < 2) sums[t] = 0.0f;
        if (t == 2) *out = 0.0f;
    }
    const int q = t & 127;
    const int rsub = t >> 7;
    const int b = blockIdx.x;
    const f32x4* __restrict__ W4 = reinterpret_cast<const f32x4*>(W) + q;

    const int r0 = b * CHUNK1;
    const int r1 = (r0 + CHUNK1 < NCLS) ? (r0 + CHUNK1) : NCLS;

    f32x4 a0 = (f32x4)(0.f), a1 = a0, a2 = a0, a3 = a0;

    if (r1 - r0 == CHUNK1) {
        // fast path: exactly 21 f32x4 loads per thread (rows r0+rsub, stride 2)
        const f32x4* base = W4 + (size_t)(r0 + rsub) * 128;   // unit = 2 rows = 256 f32x4
        f32x4 c0 = NTL(base);
        f32x4 c1 = NTL(base + 256);
        f32x4 c2 = NTL(base + 512);
        f32x4 c3 = NTL(base + 768);
        #pragma unroll
        for (int k = 1; k <= 4; ++k) {
            const f32x4* p = base + (size_t)k * 1024;
            a0 += c0;  c0 = NTL(p);
            a1 += c1;  c1 = NTL(p + 256);
            a2 += c2;  c2 = NTL(p + 512);
            a3 += c3;  c3 = NTL(p + 768);
        }
        f32x4 cl = NTL(base + 5120);          // 21st load (unit 20)
        a0 += c0; a1 += c1; a2 += c2; a3 += c3;
        a0 += cl;
    } else {
        for (int r = r0 + rsub; r < r1; r += 2) {
            a0 += NTL(W4 + (size_t)r * 128);
        }
    }
    a0 += a1 + a2 + a3;

    __shared__ f32x4 smem[128];
    if (rsub) smem[q] = a0;
    __syncthreads();
    if (!rsub) {
        a0 += smem[q];
        partialT[(size_t)q * NB1 + b] = a0;    // empty blocks write zeros
    }
}

// K2: block q (0..127) finishes colsum for its 4 columns (never written to
// memory), then computes that column-quad's slice of Sy/Si over all 256 rows.
__global__ __launch_bounds__(256, 4)
void reduce_dist(const f32x4* __restrict__ partialT,
                 const float* __restrict__ mu, const float* __restrict__ W,
                 const int* __restrict__ label, float* __restrict__ sums) {
    const int q = blockIdx.x;       // column quad 0..127
    const int t = threadIdx.x;
    const f32x4* __restrict__ p = partialT + (size_t)q * NB1;
    f32x4 s = (f32x4)(0.f);
    #pragma unroll
    for (int k = 0; k < NB1 / 256; ++k)
        s += p[t + k * 256];
    float sx = wave_reduce(s.x), sy = wave_reduce(s.y);
    float sz = wave_reduce(s.z), sw = wave_reduce(s.w);
    __shared__ f32x4 sm[4];
    __shared__ f32x4 csm;
    if ((t & 63) == 0) sm[t >> 6] = (f32x4)(sx, sy, sz, sw);
    __syncthreads();
    if (t == 0) csm = (sm[0] + sm[1]) + (sm[2] + sm[3]);
    __syncthreads();
    const f32x4 cs = csm;

    // dist slice: thread t = batch row t, columns 4q..4q+3
    const f32x4 m4 = reinterpret_cast<const f32x4*>(mu)[(size_t)t * 128 + q];
    const f32x4 w4 = reinterpret_cast<const f32x4*>(W)[(size_t)label[t] * 128 + q];
    f32x4 a = w4 - m4;
    f32x4 c = cs - w4 - m4;
    float dy2 = a.x * a.x + a.y * a.y + a.z * a.z + a.w * a.w;
    float di2 = c.x * c.x + c.y * c.y + c.z * c.z + c.w * c.w;

    __shared__ float rsm[8];
    dy2 = block_reduce(dy2, rsm);
    __syncthreads();
    di2 = block_reduce(di2, rsm);
    if (t == 0) {
        atomicAdd(&sums[0], dy2);
        atomicAdd(&sums[1], di2);
    }
}

// K3: loss = sum erf(dy/(sqrt2*std)) + erfc(di/(sqrt2*std)); one f32x4/thread.
__global__ __launch_bounds__(256, 4)
void loss_kernel(const float* __restrict__ stdv,
                 const float* __restrict__ sums,
                 float* __restrict__ out) {
    __shared__ float smem[8];
    const float dy = sqrtf(sums[0]);
    const float di = sqrtf(sums[1]);
    const float inv_sqrt2 = 0.70710678118654752f;
    const int i = blockIdx.x * 256 + threadIdx.x;     // 32768 f32x4 total
    f32x4 s4 = reinterpret_cast<const f32x4*>(stdv)[i];
    float acc;
    {
        float rx = inv_sqrt2 / s4.x, ry = inv_sqrt2 / s4.y;
        float rz = inv_sqrt2 / s4.z, rw = inv_sqrt2 / s4.w;
        acc  = erff(dy * rx) + erfcf(di * rx);
        acc += erff(dy * ry) + erfcf(di * ry);
        acc += erff(dy * rz) + erfcf(di * rz);
        acc += erff(dy * rw) + erfcf(di * rw);
    }
    acc = block_reduce(acc, smem);
    if (threadIdx.x == 0) atomicAdd(out, acc);
}

extern "C" void kernel_launch(void* const* d_in, const int* in_sizes, int n_in,
                              void* d_out, int out_size, void* d_ws, size_t ws_size,
                              hipStream_t stream) {
    // inputs: 0=x (unused), 1=mu, 2=std, 3=weight, 4=label
    const float* mu    = (const float*)d_in[1];
    const float* stdv  = (const float*)d_in[2];
    const float* W     = (const float*)d_in[3];
    const int*   label = (const int*)d_in[4];
    float* out = (float*)d_out;
    float* ws  = (float*)d_ws;
    // ws layout: [0],[1]=Sy,Si ; floats [1024 ...) = partialT (4 MB)
    float* sums = ws;
    f32x4* partialT = (f32x4*)(ws + 1024);

    colsum_partial<<<NB1, 256, 0, stream>>>(W, partialT, sums, out);
    reduce_dist<<<128, 256, 0, stream>>>(partialT, mu, W, label, sums);
    loss_kernel<<<128, 256, 0, stream>>>(stdv, sums, out);
}

// Round 9
// 43.435 us; speedup vs baseline: 1.1720x; 1.1515x over previous
//
#include <hip/hip_runtime.h>
#include <math.h>

#define DDIM 512
#define BDIM 256
#define NCLS 85742
#define NB1 2048
#define CHUNK1 ((NCLS + NB1 - 1) / NB1)   // 42 rows per block

typedef float f32x4 __attribute__((ext_vector_type(4)));

__device__ __forceinline__ float wave_reduce(float v) {
    #pragma unroll
    for (int off = 32; off > 0; off >>= 1)
        v += __shfl_down(v, off, 64);
    return v;
}

__device__ __forceinline__ float block_reduce(float v, float* smem) {
    const int lane = threadIdx.x & 63;
    const int wid  = threadIdx.x >> 6;
    v = wave_reduce(v);
    if (lane == 0) smem[wid] = v;
    __syncthreads();
    if (wid == 0) {
        v = (lane < (int)(blockDim.x >> 6)) ? smem[lane] : 0.0f;
        v = wave_reduce(v);
    }
    return v;
}

// ws float layout:
//   [0] Si_acc   [1] Sy_tot   [2] S2_tot
//   [16..143]  aux sy partials (128)
//   [144..271] aux s2 partials (128)
//   [1024 .. +131072)  Upart: f32x4 [row(256)][quad(128)]  (512 KB)
//   then partialT: f32x4 [quad(128)][block(2048)]          (4 MB)
#define WS_UPART 1024
#define WS_PART  (1024 + 256 * 128 * 4)

// K1: colsum partials over a contiguous 42-row chunk (unchanged core).
// Blocks 0..127 additionally compute the colsum-independent aux terms for
// batch rows 2b,2b+1: Sy partial, S2=sum(u^2) partial, and U rows (u=wy+mu).
// Block 0 zeroes the downstream atomic accumulators (safe: consumed in K2/K3).
__global__ __launch_bounds__(256, 4)
void colsum_partial(const float* __restrict__ W, const float* __restrict__ mu,
                    const int* __restrict__ label, float* __restrict__ ws,
                    float* __restrict__ out) {
    const int t = threadIdx.x;
    const int b = blockIdx.x;
    if (b == 0 && t < 2) {
        if (t == 0) { ws[0] = 0.0f; *out = 0.0f; }
    }
    const int q = t & 127;
    const int rsub = t >> 7;
    const f32x4* __restrict__ W4 = reinterpret_cast<const f32x4*>(W) + q;

    const int r0 = b * CHUNK1;
    const int r1 = (r0 + CHUNK1 < NCLS) ? (r0 + CHUNK1) : NCLS;

    f32x4 a0 = (f32x4)(0.f), a1 = a0, a2 = a0, a3 = a0;

    if (r1 - r0 == CHUNK1) {
        const f32x4* base = W4 + (size_t)(r0 + rsub) * 128;  // unit = 2 rows
        f32x4 c0 = base[0];
        f32x4 c1 = base[256];
        f32x4 c2 = base[512];
        f32x4 c3 = base[768];
        #pragma unroll
        for (int k = 1; k <= 4; ++k) {
            const f32x4* p = base + (size_t)k * 1024;
            a0 += c0;  c0 = p[0];
            a1 += c1;  c1 = p[256];
            a2 += c2;  c2 = p[512];
            a3 += c3;  c3 = p[768];
        }
        f32x4 cl = base[5120];
        a0 += c0; a1 += c1; a2 += c2; a3 += c3;
        a0 += cl;
    } else {
        for (int r = r0 + rsub; r < r1; r += 2)
            a0 += W4[(size_t)r * 128];
    }
    a0 += a1 + a2 + a3;

    __shared__ f32x4 smem[128];
    if (rsub) smem[q] = a0;
    __syncthreads();
    if (!rsub) {
        a0 += smem[q];
        f32x4* partialT = reinterpret_cast<f32x4*>(ws + WS_PART);
        partialT[(size_t)q * NB1 + b] = a0;   // empty blocks write zeros
    }

    // ---- aux work: blocks 0..127, batch rows 2b, 2b+1 ----
    if (b < 128) {
        const int row = 2 * b + rsub;
        const int lab = label[row];
        const f32x4 m4 = reinterpret_cast<const f32x4*>(mu)[(size_t)row * 128 + q];
        const f32x4 w4 = reinterpret_cast<const f32x4*>(W)[(size_t)lab * 128 + q];
        f32x4 d = w4 - m4;
        f32x4 u = w4 + m4;
        reinterpret_cast<f32x4*>(ws + WS_UPART)[(size_t)row * 128 + q] = u;
        float syp = d.x * d.x + d.y * d.y + d.z * d.z + d.w * d.w;
        float s2p = u.x * u.x + u.y * u.y + u.z * u.z + u.w * u.w;
        __shared__ float rsm[8];
        __syncthreads();
        syp = block_reduce(syp, rsm);
        __syncthreads();
        s2p = block_reduce(s2p, rsm);
        if (t == 0) {
            ws[16 + b]  = syp;
            ws[144 + b] = s2p;
        }
    }
}

// K2: block q finishes colsum for its 4 columns and computes its share of
// Si's expansion: si_q = sum_d (256*cs_d^2 - 2*cs_d*U_d). Block 0 reduces the
// aux Sy/S2 partials to scalars.
__global__ __launch_bounds__(256, 4)
void reduce_kernel(float* __restrict__ ws) {
    const int q = blockIdx.x;       // 0..127
    const int t = threadIdx.x;
    const f32x4* __restrict__ partialT =
        reinterpret_cast<const f32x4*>(ws + WS_PART) + (size_t)q * NB1;
    f32x4 s = (f32x4)(0.f);
    #pragma unroll
    for (int k = 0; k < NB1 / 256; ++k)
        s += partialT[t + k * 256];
    // U partial: row t, quad q
    f32x4 u = reinterpret_cast<const f32x4*>(ws + WS_UPART)[(size_t)t * 128 + q];

    float sx = wave_reduce(s.x), sy = wave_reduce(s.y);
    float sz = wave_reduce(s.z), sw = wave_reduce(s.w);
    float ux = wave_reduce(u.x), uy = wave_reduce(u.y);
    float uz = wave_reduce(u.z), uw = wave_reduce(u.w);
    __shared__ f32x4 sm[4], um[4];
    if ((t & 63) == 0) {
        sm[t >> 6] = (f32x4)(sx, sy, sz, sw);
        um[t >> 6] = (f32x4)(ux, uy, uz, uw);
    }
    __syncthreads();
    if (t == 0) {
        f32x4 cs = (sm[0] + sm[1]) + (sm[2] + sm[3]);
        f32x4 U  = (um[0] + um[1]) + (um[2] + um[3]);
        f32x4 si4 = 256.0f * cs * cs - 2.0f * cs * U;
        atomicAdd(&ws[0], si4.x + si4.y + si4.z + si4.w);
    }

    if (q == 0) {
        __syncthreads();
        __shared__ float rsm[8];
        float syp = (t < 128) ? ws[16 + t]  : 0.0f;
        float s2p = (t < 128) ? ws[144 + t] : 0.0f;
        syp = block_reduce(syp, rsm);
        __syncthreads();
        s2p = block_reduce(s2p, rsm);
        if (t == 0) { ws[1] = syp; ws[2] = s2p; }
    }
}

// K3: loss = sum erf(dy/(sqrt2*std)) + erfc(di/(sqrt2*std)); one f32x4/thread.
__global__ __launch_bounds__(256, 4)
void loss_kernel(const float* __restrict__ stdv, const float* __restrict__ ws,
                 float* __restrict__ out) {
    __shared__ float smem[8];
    const float dy = sqrtf(ws[1]);
    const float di = sqrtf(ws[0] + ws[2]);    // Si = Si_acc + S2
    const float inv_sqrt2 = 0.70710678118654752f;
    const int i = blockIdx.x * 256 + threadIdx.x;     // 32768 f32x4 total
    f32x4 s4 = reinterpret_cast<const f32x4*>(stdv)[i];
    float acc;
    {
        float rx = inv_sqrt2 / s4.x, ry = inv_sqrt2 / s4.y;
        float rz = inv_sqrt2 / s4.z, rw = inv_sqrt2 / s4.w;
        acc  = erff(dy * rx) + erfcf(di * rx);
        acc += erff(dy * ry) + erfcf(di * ry);
        acc += erff(dy * rz) + erfcf(di * rz);
        acc += erff(dy * rw) + erfcf(di * rw);
    }
    acc = block_reduce(acc, smem);
    if (threadIdx.x == 0) atomicAdd(out, acc);
}

extern "C" void kernel_launch(void* const* d_in, const int* in_sizes, int n_in,
                              void* d_out, int out_size, void* d_ws, size_t ws_size,
                              hipStream_t stream) {
    // inputs: 0=x (unused), 1=mu, 2=std, 3=weight, 4=label
    const float* mu    = (const float*)d_in[1];
    const float* stdv  = (const float*)d_in[2];
    const float* W     = (const float*)d_in[3];
    const int*   label = (const int*)d_in[4];
    float* out = (float*)d_out;
    float* ws  = (float*)d_ws;

    colsum_partial<<<NB1, 256, 0, stream>>>(W, mu, label, ws, out);
    reduce_kernel<<<128, 256, 0, stream>>>(ws);
    loss_kernel<<<128, 256, 0, stream>>>(stdv, ws, out);
}